// Round 1
// 480.085 us; speedup vs baseline: 1.0313x; 1.0313x over previous
//
#include <hip/hip_runtime.h>

typedef __bf16 bf16;
typedef __attribute__((ext_vector_type(8))) __bf16 bf16x8;
typedef __attribute__((ext_vector_type(4))) __bf16 bf16x4;
typedef __attribute__((ext_vector_type(4))) float f32x4;

#define B_  32
#define S_  2048
#define DC  1024
#define DQ  1024
#define H_  512
#define M_  (B_*S_)

#define BM  128
#define BN  512            // full H per block -> ctx fetched exactly once
#define BK  32
#define NCH 32             // s-chunks for expected_ctx

// async global->LDS, 16B per lane
#define GLD16(g, l) __builtin_amdgcn_global_load_lds( \
    (__attribute__((address_space(1))) void*)(g),     \
    (__attribute__((address_space(3))) void*)(l), 16, 0, 0)

// ---------- Prep: blocks 0..255 = Wc->bf16 transpose tiles; 256..511 = qb GEMV ----------
// WcT2 layout: [kb(32)][h(512)][kk(32)] bf16, with the 8-element kk-chunk index
// XOR-swizzled by ((h>>1)&3) so that k_gemm's linear global_load_lds staging +
// swizzled ds_read_b128 is 2-way-conflict-free (T2, both-sides involution).
__global__ __launch_bounds__(256) void k_prep(const float* __restrict__ W1,
                                              const float* __restrict__ query,
                                              const float* __restrict__ b1,
                                              bf16* __restrict__ WcT2,
                                              float* __restrict__ qb) {
    const int bid = blockIdx.x, tid = threadIdx.x;
    if (bid < 256) {
        // W1[:1024] (k-major) -> WcT2 [kb][h][kk^swz] bf16
        __shared__ bf16 t[32 * 68];            // [kk][h-in-tile], pad 4
        const int kb = bid >> 3;               // 0..31
        const int cb = bid & 7;                // 0..7, 64-col tile
        #pragma unroll
        for (int i = 0; i < 2; ++i) {
            int idx = i * 256 + tid;           // 0..511
            int k  = idx >> 4;                 // 0..31
            int h4 = (idx & 15) * 4;           // 0..60
            const float4 v = *(const float4*)(W1 + ((size_t)(kb * 32 + k)) * H_ + cb * 64 + h4);
            bf16x4 pk = { (bf16)v.x, (bf16)v.y, (bf16)v.z, (bf16)v.w };
            *(bf16x4*)(&t[k * 68 + h4]) = pk;
        }
        __syncthreads();
        const int col = tid >> 2;              // 0..63
        const int kk0 = (tid & 3) * 8;         // 0,8,16,24
        bf16x8 o;
        #pragma unroll
        for (int j = 0; j < 8; ++j) o[j] = t[(kk0 + j) * 68 + col];
        const int kk0s = kk0 ^ (((col >> 1) & 3) << 3);   // pre-swizzle chunk position
        *(bf16x8*)(WcT2 + (size_t)kb * 16384 + (size_t)(cb * 64 + col) * 32 + kk0s) = o;
    } else {
        // qb[b][h] = query[b,:] . Wq[:,h] + b1[h]
        const int r = bid - 256;
        const int hblk = r & 7;                // 0..7
        const int b    = r >> 3;               // 0..31
        __shared__ float q[DQ];
        __shared__ float red[256];
        #pragma unroll
        for (int i = 0; i < 4; ++i)
            q[tid + i * 256] = query[(size_t)b * DQ + tid + i * 256];
        __syncthreads();
        const int h  = hblk * 64 + (tid & 63);
        const int kc = tid >> 6;               // 0..3
        const float* w = W1 + (size_t)DC * H_ + (size_t)(kc * 256) * H_ + h;
        const float* qv = q + kc * 256;
        float acc = 0.0f;
        #pragma unroll 8
        for (int k = 0; k < 256; ++k)
            acc = fmaf(qv[k], w[(size_t)k * H_], acc);
        red[tid] = acc;
        __syncthreads();
        if (tid < 64)
            qb[(size_t)b * H_ + hblk * 64 + tid] =
                red[tid] + red[tid + 64] + red[tid + 128] + red[tid + 192] + b1[hblk * 64 + tid];
    }
}

// ---------- Kernel G: score[row] = sum_h tanh(ctx@Wc + qb)[h]*w2[h] ----------
// 512 blocks, 512 thr = 8 waves (2m x 4n), wave tile 64x128.
// 3-deep LDS pipeline, ALL staging via global_load_lds (A staged as f32,
// converted at fragment-read). Counted s_waitcnt vmcnt(6) + raw s_barrier:
// loads for step k+2 stay in flight across the barrier (T3+T4); XOR-swizzled
// LDS for conflict-free ds_read_b128 (T2); setprio around MFMA (T5).
//
// LDS: Af = 3 x [128][32] f32 (48 KB), Bh = 3 x [512][32] bf16 (96 KB).
// A swizzle (128B rows): 16B-chunk c stored at c ^ (row&7)   [global src pre-swizzled]
// B swizzle (64B rows):  8-elem chunk stored at c ^ ((row>>1)&3) [WcT2 pre-swizzled]
__global__ __launch_bounds__(512, 2) void k_gemm(const float* __restrict__ ctx,
                                                 const bf16*  __restrict__ WcT2,
                                                 const float* __restrict__ qb,
                                                 const float* __restrict__ W2,
                                                 float* __restrict__ score) {
    __shared__ char smem_raw[147456];
    float* Af = (float*)smem_raw;                 // 3 x 4096 f32
    bf16*  Bh = (bf16*)(smem_raw + 49152);        // 3 x 16384 bf16
    float* red = (float*)smem_raw;                // epilogue reuse

    const int tid  = threadIdx.x;
    const int mblk = blockIdx.x;
    const size_t row_base = (size_t)mblk * BM;
    const int b = mblk >> 4;

    const int lane = tid & 63;
    const int wv   = tid >> 6;
    const int wm   = wv & 1;
    const int wn   = wv >> 1;
    const int l16  = lane & 15;
    const int quad = lane >> 4;

    f32x4 acc[4][8] = {};

    // ---- staging addresses (all global_load_lds; LDS dest linear per wave) ----
    // A: 2 instrs/thread, each wave-instr covers 8 rows x 128B. Source column
    // chunk pre-swizzled by row&7 so LDS holds the swizzled layout.
    const int arow0  = wv * 8 + (lane >> 3);              // rows 0..63 (instr 0)
    const int acolsw = ((lane & 7) ^ ((lane >> 3) & 7)) * 4;
    const float* asrc0 = ctx + (row_base + arow0) * (size_t)DC + acolsw;
    const float* asrc1 = asrc0 + (size_t)64 * DC;         // rows 64..127 (instr 1)
    const int adst0 = wv * 256 + lane * 4;                // floats within A buffer
    const int adst1 = adst0 + 2048;
    const bf16* bsrcB = WcT2 + tid * 8;
    const int  boff   = tid * 8;

    // ---- fragment read offsets (physical addr of the LOGICAL lo-chunk) ----
    const int a0 = (wm * 64 + l16) * 32 + (((quad * 2) ^ (l16 & 7)) * 4);       // f32 idx
    const int b0 = (wn * 128 + l16) * 32 + ((quad * 8) ^ (((l16 >> 1) & 3) << 3)); // bf16 idx

#define KSTEP(KB, RD, WR, ISSUE)                                               \
  {                                                                            \
    if (ISSUE) {                                                               \
      _Pragma("unroll")                                                        \
      for (int i = 0; i < 4; ++i)                                              \
        GLD16(bsrcB + (size_t)((KB) + 2) * 16384 + i * 4096,                   \
              Bh + (WR) * 16384 + boff + i * 4096);                            \
      GLD16(asrc0 + (size_t)((KB) + 2) * 32, Af + (WR) * 4096 + adst0);        \
      GLD16(asrc1 + (size_t)((KB) + 2) * 32, Af + (WR) * 4096 + adst1);        \
    }                                                                          \
    bf16x8 aF[4], bF[8];                                                       \
    _Pragma("unroll")                                                          \
    for (int mf = 0; mf < 4; ++mf) {                                           \
      const f32x4 lo = *(const f32x4*)(Af + (RD) * 4096 + (a0 + mf * 512));    \
      const f32x4 hi = *(const f32x4*)(Af + (RD) * 4096 + ((a0 ^ 4) + mf * 512)); \
      bf16x8 t;                                                                \
      t[0] = (bf16)lo[0]; t[1] = (bf16)lo[1]; t[2] = (bf16)lo[2]; t[3] = (bf16)lo[3]; \
      t[4] = (bf16)hi[0]; t[5] = (bf16)hi[1]; t[6] = (bf16)hi[2]; t[7] = (bf16)hi[3]; \
      aF[mf] = t;                                                              \
    }                                                                          \
    _Pragma("unroll")                                                          \
    for (int nf = 0; nf < 8; ++nf)                                             \
      bF[nf] = *(const bf16x8*)(Bh + (RD) * 16384 + (b0 + nf * 512));          \
    __builtin_amdgcn_s_setprio(1);                                             \
    _Pragma("unroll")                                                          \
    for (int mf = 0; mf < 4; ++mf)                                             \
      _Pragma("unroll")                                                        \
      for (int nf = 0; nf < 8; ++nf)                                           \
        acc[mf][nf] = __builtin_amdgcn_mfma_f32_16x16x32_bf16(aF[mf], bF[nf],  \
                                                              acc[mf][nf], 0, 0, 0); \
    __builtin_amdgcn_s_setprio(0);                                             \
  }

#define WAITBAR(N)                                                             \
    asm volatile("s_waitcnt vmcnt(" #N ")" ::: "memory");                      \
    __builtin_amdgcn_s_barrier();                                              \
    __builtin_amdgcn_sched_barrier(0);

    // ---- prologue: stage k-steps 0 and 1 (12 loads in flight) ----
    #pragma unroll
    for (int i = 0; i < 4; ++i)
        GLD16(bsrcB + i * 4096, Bh + boff + i * 4096);
    GLD16(asrc0, Af + adst0);
    GLD16(asrc1, Af + adst1);
    #pragma unroll
    for (int i = 0; i < 4; ++i)
        GLD16(bsrcB + 16384 + i * 4096, Bh + 16384 + boff + i * 4096);
    GLD16(asrc0 + 32, Af + 4096 + adst0);
    GLD16(asrc1 + 32, Af + 4096 + adst1);
    WAITBAR(6)                 // step 0 landed; step 1's 6 loads stay in flight

    // ---- steady state: kb = 0..29, rotate 3 buffers, never drain to 0 ----
    #pragma unroll 1
    for (int t3 = 0; t3 < 10; ++t3) {
        const int kb = t3 * 3;
        KSTEP(kb + 0, 0, 2, 1)
        WAITBAR(6)
        KSTEP(kb + 1, 1, 0, 1)
        WAITBAR(6)
        KSTEP(kb + 2, 2, 1, 1)
        WAITBAR(6)
    }
    // ---- tail: kb = 30 (drain), kb = 31 ----
    KSTEP(30, 0, 0, 0)
    asm volatile("s_waitcnt vmcnt(0)" ::: "memory");
    __builtin_amdgcn_s_barrier();
    __builtin_amdgcn_sched_barrier(0);
    KSTEP(31, 1, 0, 0)
    __syncthreads();

#undef KSTEP
#undef WAITBAR

    // ---- epilogue: s(row) = sum over this wave's 128 cols of tanh(acc+qb)*w2 ----
    float qv[8], wvv[8];
    #pragma unroll
    for (int nf = 0; nf < 8; ++nf) {
        int c = wn * 128 + nf * 16 + l16;
        qv[nf]  = qb[(size_t)b * H_ + c];
        wvv[nf] = W2[c];
    }
    #pragma unroll
    for (int mf = 0; mf < 4; ++mf) {
        #pragma unroll
        for (int r = 0; r < 4; ++r) {
            float s = 0.0f;
            #pragma unroll
            for (int nf = 0; nf < 8; ++nf) {
                float x = acc[mf][nf][r] + qv[nf];
                float t = 1.0f - 2.0f / (1.0f + __expf(2.0f * x)); // tanh, saturates
                s = fmaf(t, wvv[nf], s);
            }
            s += __shfl_xor(s, 1);
            s += __shfl_xor(s, 2);
            s += __shfl_xor(s, 4);
            s += __shfl_xor(s, 8);
            if (l16 == 0)
                red[(wm * 64 + mf * 16 + quad * 4 + r) * 4 + wn] = s;
        }
    }
    __syncthreads();
    if (tid < BM)
        score[row_base + tid] = red[tid * 4] + red[tid * 4 + 1] + red[tid * 4 + 2] + red[tid * 4 + 3];
}

// ---------- Kernel S: + b2, mask, stable softmax per batch row ----------
__global__ __launch_bounds__(256) void k_softmax(const float* __restrict__ score,
                                                 const float* __restrict__ b2,
                                                 const int*   __restrict__ mask,
                                                 float* __restrict__ p_out) {
    int b = blockIdx.x, tid = threadIdx.x;
    __shared__ float red[256];
    float loc[8];
    float b2v = b2[0];
    float mx = -1e30f;
    #pragma unroll
    for (int i = 0; i < 8; ++i) {
        size_t r = (size_t)b * S_ + i * 256 + tid;
        float v = score[r] + b2v;
        if (mask[r] == 0) v = -10000.0f;
        loc[i] = v;
        mx = fmaxf(mx, v);
    }
    red[tid] = mx; __syncthreads();
    for (int o = 128; o > 0; o >>= 1) {
        if (tid < o) red[tid] = fmaxf(red[tid], red[tid + o]);
        __syncthreads();
    }
    mx = red[0]; __syncthreads();
    float se = 0.0f;
    #pragma unroll
    for (int i = 0; i < 8; ++i) {
        float e = __expf(loc[i] - mx);
        loc[i] = e;
        se += e;
    }
    red[tid] = se; __syncthreads();
    for (int o = 128; o > 0; o >>= 1) {
        if (tid < o) red[tid] += red[tid + o];
        __syncthreads();
    }
    float inv = 1.0f / red[0];
    #pragma unroll
    for (int i = 0; i < 8; ++i)
        p_out[(size_t)b * S_ + i * 256 + tid] = loc[i] * inv;
}

// ---------- Kernel E: partial expected_ctx over 64-row s-chunks ----------
__global__ __launch_bounds__(256) void k_expected(const float* __restrict__ ctx,
                                                  const float* __restrict__ p,
                                                  float* __restrict__ partial) {
    int b = blockIdx.x, ch = blockIdx.y, tid = threadIdx.x;
    __shared__ float ps[64];
    if (tid < 64) ps[tid] = p[(size_t)b * S_ + ch * 64 + tid];
    __syncthreads();
    const float* base = ctx + ((size_t)b * S_ + ch * 64) * DC + tid * 4;
    float ax = 0.f, ay = 0.f, az = 0.f, aw = 0.f;
    #pragma unroll 8
    for (int s = 0; s < 64; ++s) {
        const float4 v = *(const float4*)(base + (size_t)s * DC);
        float w = ps[s];
        ax = fmaf(w, v.x, ax);
        ay = fmaf(w, v.y, ay);
        az = fmaf(w, v.z, az);
        aw = fmaf(w, v.w, aw);
    }
    float4 o = { ax, ay, az, aw };
    *(float4*)(partial + ((size_t)(b * NCH + ch)) * DC + tid * 4) = o;
}

// ---------- Kernel R: reduce chunks -> expected_ctx ----------
__global__ __launch_bounds__(256) void k_reduce(const float* __restrict__ partial,
                                                float* __restrict__ out) {
    int b = blockIdx.x, tid = threadIdx.x;
    float4 acc = { 0.f, 0.f, 0.f, 0.f };
    #pragma unroll
    for (int c = 0; c < NCH; ++c) {
        const float4 v = *(const float4*)(partial + ((size_t)(b * NCH + c)) * DC + tid * 4);
        acc.x += v.x; acc.y += v.y; acc.z += v.z; acc.w += v.w;
    }
    *(float4*)(out + (size_t)b * DC + tid * 4) = acc;
}

extern "C" void kernel_launch(void* const* d_in, const int* in_sizes, int n_in,
                              void* d_out, int out_size, void* d_ws, size_t ws_size,
                              hipStream_t stream) {
    (void)in_sizes; (void)n_in; (void)out_size; (void)ws_size;
    const float* ctx   = (const float*)d_in[0];
    const float* query = (const float*)d_in[1];
    const float* W1    = (const float*)d_in[2];
    const float* b1    = (const float*)d_in[3];
    const float* W2    = (const float*)d_in[4];
    const float* b2    = (const float*)d_in[5];
    const int*   mask  = (const int*)d_in[6];

    float* out      = (float*)d_out;
    float* expected = out;                 // 32*1024
    float* p_out    = out + 32768;         // 32*2048

    char* w = (char*)d_ws;
    bf16*  WcT2      = (bf16*)w;                                    // 1 MB  [kb][h][kk^swz]
    float* qb        = (float*)(w + (1 << 20));                     // 64 KB
    float* score     = (float*)(w + (1 << 20) + (64 << 10));        // 256 KB
    float* partial_e = (float*)(w + (1 << 20) + (320 << 10));       // 4 MB

    k_prep    <<<512, 256, 0, stream>>>(W1, query, b1, WcT2, qb);
    k_gemm    <<<512, 512, 0, stream>>>(ctx, WcT2, qb, W2, score);
    k_softmax <<<B_, 256, 0, stream>>>(score, b2, mask, p_out);
    k_expected<<<dim3(B_, NCH), 256, 0, stream>>>(ctx, p_out, partial_e);
    k_reduce  <<<B_, 256, 0, stream>>>(partial_e, expected);
}